// Round 1
// baseline (820.519 us; speedup 1.0000x reference)
//
#include <hip/hip_runtime.h>

#define PI2 6.28318530717958647692f

// Sizes: B=8, C=128 (CIN=COUT=HC, NH=1), H=W=256, modes M1=M2=32, Wf=129.
// Pipeline:
//  kInitE   : E[256][64], E[w][2m]=cos(2pi m w/256), E[w][2m+1]=-sin(...)
//  kFcT     : fcwT[c][o] = fc_w[o][c]
//  kRowDFT  : T1[r][m] (complex, r = (b*128+i)*256+h) = rfft over w, keep m<32   (GEMM [262144,256]@[256,64])
//  kColDFT  : Xm[nm][i][b] = fft over h of T1, keep n<32 (nm = n*32+m)
//  kTransW  : Wt[nm][i*128+o] = w[i][o][n][m]
//  kModeMM  : Y[nm][o][b] = sum_i Xm[nm][i][b] * Wt[nm][i*128+o]
//  kFC      : Y2[b][o'][n][m] = sum_o fcwT[o][o'] * Y[nm][o][b]      (fc fused in spectral domain)
//  kInv     : out[b][o][h][w] = irfft2-sparse(Y2) + fc_b[o]
//
// Scratch: T1(64MB), Wt(64MB), Xm(8MB), Y(8MB) placed inside d_out (dead before kInv
// overwrites d_out). d_ws holds only Y2 (8MB) + E + fcwT (128KB).

__global__ void kInitE(float* __restrict__ E) {
  int tid = blockIdx.x * 256 + threadIdx.x;   // 16384
  int w = tid >> 6, cc = tid & 63, m = cc >> 1;
  float ang = (PI2 / 256.0f) * (float)((m * w) & 255);
  float s, c;
  sincosf(ang, &s, &c);
  E[tid] = (cc & 1) ? -s : c;
}

__global__ void kFcT(const float* __restrict__ fcw, float* __restrict__ fcwT) {
  int tid = blockIdx.x * 256 + threadIdx.x;   // 16384
  int c = tid >> 7, o = tid & 127;
  fcwT[tid] = fcw[o * 128 + c];               // fcwT[c][o] = fc_w[o][c]
}

// ---------------- forward row DFT as GEMM: T1[262144,64] = x[262144,256] @ E[256,64]
__global__ __launch_bounds__(256) void kRowDFT(const float* __restrict__ x,
                                               const float* __restrict__ E,
                                               float* __restrict__ T1) {
  __shared__ float As[64][36];   // [row][k], pad to 36 (16B-aligned rows, bank spread)
  __shared__ float Bs[32][64];   // [k][col]
  const int t = threadIdx.x;
  const int r0 = blockIdx.x * 64;
  const int tx = t & 15, ty = t >> 4;   // col tile 4*tx, row tile 4*ty
  float acc[4][4] = {};
  for (int kc = 0; kc < 256; kc += 32) {
    for (int l = t; l < 512; l += 256) {       // 64 rows x 8 float4
      int row = l >> 3, c4 = (l & 7) * 4;
      *(float4*)&As[row][c4] = *(const float4*)&x[(r0 + row) * 256 + kc + c4];
    }
    for (int l = t; l < 512; l += 256) {       // 32 k x 16 float4
      int k = l >> 4, c4 = (l & 15) * 4;
      *(float4*)&Bs[k][c4] = *(const float4*)&E[(kc + k) * 64 + c4];
    }
    __syncthreads();
    for (int k = 0; k < 32; k += 4) {
      float a[4][4];
      #pragma unroll
      for (int i = 0; i < 4; ++i)
        *(float4*)&a[i][0] = *(const float4*)&As[4 * ty + i][k];
      #pragma unroll
      for (int kk = 0; kk < 4; ++kk) {
        float bv[4];
        *(float4*)bv = *(const float4*)&Bs[k + kk][4 * tx];
        #pragma unroll
        for (int i = 0; i < 4; ++i)
          #pragma unroll
          for (int j = 0; j < 4; ++j)
            acc[i][j] += a[i][kk] * bv[j];
      }
    }
    __syncthreads();
  }
  #pragma unroll
  for (int i = 0; i < 4; ++i) {
    float4 v = {acc[i][0], acc[i][1], acc[i][2], acc[i][3]};
    *(float4*)&T1[(r0 + 4 * ty + i) * 64 + 4 * tx] = v;
  }
}

// ---------------- forward column DFT: Xm[nm][i][b] = sum_h T1[(bi,h)][m] e^{-2pi i n h/256}
__global__ __launch_bounds__(256) void kColDFT(const float* __restrict__ T1,
                                               float2* __restrict__ Xm) {
  __shared__ float4 Ts4[4096];   // == float2 Ts[256][32]
  const int t = threadIdx.x;
  const int bi = blockIdx.x;     // b*128 + i
  for (int l = t; l < 4096; l += 256)
    Ts4[l] = *(const float4*)&T1[bi * 16384 + l * 4];
  __syncthreads();
  const float2* Ts = (const float2*)Ts4;
  const int n = t >> 3, mb = t & 7;
  float s_, c_;
  sincosf((PI2 / 256.0f) * (float)n, &s_, &c_);
  const float dc = c_, dsn = -s_;            // e^{-2pi i n/256}
  float cr = 1.0f, ci = 0.0f;
  float ar[4] = {}, ai[4] = {};
  for (int h = 0; h < 256; ++h) {
    #pragma unroll
    for (int j = 0; j < 4; ++j) {
      float2 tv = Ts[h * 32 + mb + 8 * j];
      ar[j] += tv.x * cr - tv.y * ci;
      ai[j] += tv.x * ci + tv.y * cr;
    }
    float nc = cr * dc - ci * dsn;
    ci = cr * dsn + ci * dc;
    cr = nc;
  }
  const int b = bi >> 7, i = bi & 127;
  #pragma unroll
  for (int j = 0; j < 4; ++j) {
    int nm = n * 32 + mb + 8 * j;
    Xm[nm * 1024 + i * 8 + b] = make_float2(ar[j], ai[j]);
  }
}

// ---------------- transpose weight: Wt[nm][io] = w[io][nm]
__global__ __launch_bounds__(256) void kTransW(const float* __restrict__ wgt,
                                               float* __restrict__ Wt) {
  __shared__ float tile[32][33];
  const int t = threadIdx.x;
  const int bx = blockIdx.x & 31;    // nm tile (32 tiles)
  const int by = blockIdx.x >> 5;    // io tile (512 tiles)
  const int tx = t & 31, ty = t >> 5;
  #pragma unroll
  for (int k = 0; k < 4; ++k) {
    int row = ty + 8 * k;
    tile[row][tx] = wgt[(by * 32 + row) * 1024 + bx * 32 + tx];
  }
  __syncthreads();
  #pragma unroll
  for (int k = 0; k < 4; ++k) {
    int row = ty + 8 * k;
    Wt[(bx * 32 + row) * 16384 + by * 32 + tx] = tile[tx][row];
  }
}

// ---------------- per-mode channel matmul: Y[nm][o][b] = sum_i Xm[nm][i][b]*Wt[nm][i*128+o]
__global__ __launch_bounds__(256) void kModeMM(const float2* __restrict__ Xm,
                                               const float* __restrict__ Wt,
                                               float2* __restrict__ Y) {
  const int t = threadIdx.x;
  const int o = t & 127;
  int nm = blockIdx.x * 2 + (t >> 7);
  nm = __builtin_amdgcn_readfirstlane(nm);   // wave-uniform -> scalar loads of Xm
  const float2* Xs = Xm + nm * 1024;         // [i*8 + b]
  const float* Wr = Wt + nm * 16384;
  float accr[8] = {}, acci[8] = {};
  for (int i = 0; i < 128; ++i) {
    float wv = Wr[i * 128 + o];
    #pragma unroll
    for (int b = 0; b < 8; ++b) {
      float2 xv = Xs[i * 8 + b];             // uniform -> s_load
      accr[b] += xv.x * wv;
      acci[b] += xv.y * wv;
    }
  }
  float2* Yp = Y + nm * 1024 + o * 8;
  #pragma unroll
  for (int b = 0; b < 8; ++b) Yp[b] = make_float2(accr[b], acci[b]);
}

// ---------------- fc in spectral domain: Y2[b][o'][nm] = sum_o fcwT[o][o'] * Y[nm][o][b]
__global__ __launch_bounds__(256) void kFC(const float2* __restrict__ Y,
                                           const float* __restrict__ fcwT,
                                           float2* __restrict__ Y2) {
  const int t = threadIdx.x;
  const int op = t & 127;
  int nm = blockIdx.x * 2 + (t >> 7);
  nm = __builtin_amdgcn_readfirstlane(nm);
  const float2* Ys = Y + nm * 1024;          // [o*8 + b]
  float accr[8] = {}, acci[8] = {};
  for (int o = 0; o < 128; ++o) {
    float fv = fcwT[o * 128 + op];
    #pragma unroll
    for (int b = 0; b < 8; ++b) {
      float2 yv = Ys[o * 8 + b];             // uniform -> s_load
      accr[b] += yv.x * fv;
      acci[b] += yv.y * fv;
    }
  }
  #pragma unroll
  for (int b = 0; b < 8; ++b)
    Y2[(b * 128 + op) * 1024 + nm] = make_float2(accr[b], acci[b]);
}

// ---------------- sparse irfft2 + bias: one block per (b,o)
// ph2: Z[h][m] = sum_n Y2[n][m] e^{+2pi i n h/256}   (thread t owns h=t, Z in regs)
// ph3: out[h][w] = fcb + (1/65536)*(Zr[0] + 2*sum_{m>=1}(Zr cos - Zi sin))
//      via quad symmetry {q, 128-q, 128+q, 256-q}; w=64,192 handled specially.
__global__ __launch_bounds__(256, 2) void kInv(const float2* __restrict__ Y2,
                                               const float* __restrict__ fcb,
                                               float* __restrict__ out) {
  __shared__ float twc[256], tws[256];
  __shared__ float tile[256][33];
  const int t = threadIdx.x;
  const int bo = blockIdx.x;
  {
    float s, c;
    sincosf((PI2 / 256.0f) * (float)t, &s, &c);
    twc[t] = c;
    tws[t] = s;
  }
  __syncthreads();
  const float2* Yp = Y2 + bo * 1024;
  float Zr[32] = {}, Zi[32] = {};
  {
    const float dc = twc[t], dsn = tws[t];   // e^{+2pi i h/256}, h = t
    float cr = 1.0f, ci = 0.0f;
    for (int n = 0; n < 32; ++n) {
      #pragma unroll
      for (int m = 0; m < 32; ++m) {
        float2 yv = Yp[n * 32 + m];          // uniform across wave -> s_load
        Zr[m] += yv.x * cr - yv.y * ci;
        Zi[m] += yv.x * ci + yv.y * cr;
      }
      float nc = cr * dc - ci * dsn;
      ci = cr * dsn + ci * dc;
      cr = nc;
    }
  }
  const float INVS = 1.0f / 32768.0f;        // folds 1/(H*W) and the x2 of c2r
  #pragma unroll
  for (int m = 0; m < 32; ++m) { Zr[m] *= INVS; Zi[m] *= INVS; }
  const float base = fcb[bo & 127] - 0.5f * Zr[0];   // -Zr0/65536 corrects m=0 coef (1 not 2)
  float* po = out + bo * 65536;

  for (int cch = 0; cch < 8; ++cch) {
    float cq[8], sq[8], dcq[8], dsq[8];
    float Pe[8] = {}, Po[8] = {}, Qe[8] = {}, Qo[8] = {};
    #pragma unroll
    for (int j = 0; j < 8; ++j) {
      int q = 8 * cch + j;
      cq[j] = 1.0f; sq[j] = 0.0f;
      dcq[j] = twc[q]; dsq[j] = tws[q];      // e^{+2pi i q/256}
    }
    #pragma unroll
    for (int m = 0; m < 32; ++m) {
      #pragma unroll
      for (int j = 0; j < 8; ++j) {
        if (m & 1) { Po[j] += Zr[m] * cq[j]; Qo[j] += Zi[m] * sq[j]; }
        else       { Pe[j] += Zr[m] * cq[j]; Qe[j] += Zi[m] * sq[j]; }
        float nc = cq[j] * dcq[j] - sq[j] * dsq[j];
        sq[j] = cq[j] * dsq[j] + sq[j] * dcq[j];
        cq[j] = nc;
      }
    }
    #pragma unroll
    for (int j = 0; j < 8; ++j) {
      float Pp = Pe[j] + Po[j], Pm = Pe[j] - Po[j];
      float Qp = Qe[j] + Qo[j], Qm = Qe[j] - Qo[j];
      tile[t][j]            = base + Pp - Qp;   // w = 8c + j          (q)
      tile[t][8 + (7 - j)]  = base + Pm + Qm;   // w = 128 - q
      tile[t][16 + j]       = base + Pm - Qm;   // w = 128 + q
      tile[t][24 + (7 - j)] = base + Pp + Qp;   // w = 256 - q (mod 256)
    }
    __syncthreads();
    for (int l = t; l < 8192; l += 256) {
      int h2 = l >> 5, col = l & 31;
      int w;
      if (col < 8)       w = 8 * cch + col;
      else if (col < 16) w = (121 - 8 * cch) + (col - 8);
      else if (col < 24) w = 128 + 8 * cch + (col - 16);
      else               w = (249 - 8 * cch) + (col - 24);
      w &= 255;
      po[h2 * 256 + w] = tile[h2][col];
    }
    __syncthreads();
  }
  // specials w = 64, 192: cos(pi m/2) pattern
  float s64 = 0.0f, s192 = 0.0f;
  #pragma unroll
  for (int m = 0; m < 32; ++m) {
    int r = m & 3;
    if (r == 0)      { s64 += Zr[m]; s192 += Zr[m]; }
    else if (r == 1) { s64 -= Zi[m]; s192 += Zi[m]; }
    else if (r == 2) { s64 -= Zr[m]; s192 -= Zr[m]; }
    else             { s64 += Zi[m]; s192 -= Zi[m]; }
  }
  po[t * 256 + 64]  = base + s64;
  po[t * 256 + 192] = base + s192;
}

extern "C" void kernel_launch(void* const* d_in, const int* in_sizes, int n_in,
                              void* d_out, int out_size, void* d_ws, size_t ws_size,
                              hipStream_t stream) {
  const float* x   = (const float*)d_in[0];   // [8,128,256,256]
  const float* wgt = (const float*)d_in[1];   // [1,128,128,32,32]
  const float* fcw = (const float*)d_in[2];   // [128,128]
  const float* fcb = (const float*)d_in[3];   // [128]
  float* out = (float*)d_out;                 // 64Mi floats

  // big scratch inside d_out (all dead before kInv writes out)
  float*  T1 = out;                               // [0, 16Mi) floats
  float*  Wt = out + (16u << 20);                 // [16Mi, 32Mi)
  float2* Xm = (float2*)(out + (32u << 20));      // [32Mi, 34Mi)
  float2* Y  = (float2*)(out + (34u << 20));      // [34Mi, 36Mi)
  // d_ws: Y2 (read while kInv writes d_out) + tables. 8.13 MiB total.
  float2* Y2   = (float2*)d_ws;                   // 1Mi float2
  float*  E    = (float*)d_ws + (2u << 20);
  float*  fcwT = E + 16384;

  kInitE <<<64, 256, 0, stream>>>(E);
  kFcT   <<<64, 256, 0, stream>>>(fcw, fcwT);
  kRowDFT<<<4096, 256, 0, stream>>>(x, E, T1);
  kColDFT<<<1024, 256, 0, stream>>>(T1, Xm);
  kTransW<<<16384, 256, 0, stream>>>(wgt, Wt);
  kModeMM<<<512, 256, 0, stream>>>(Xm, Wt, Y);
  kFC    <<<512, 256, 0, stream>>>(Y, fcwT, Y2);
  kInv   <<<1024, 256, 0, stream>>>(Y2, fcb, out);
}